// Round 1
// baseline (1280.364 us; speedup 1.0000x reference)
//
#include <hip/hip_runtime.h>
#include <math.h>

#define B_ 2
#define S_ 1024
#define D_ 512
#define N_ 4096
#define H_ 8
#define DH_ 64
#define NCAND 288   // 9 neighbor cells * 32 entries
#define TOPK 32
#define NTOK (B_*S_)   // 2048

// ---------- block-wide reductions (256 threads = 4 waves) ----------
__device__ __forceinline__ float blk_sum(float v, float* sc) {
    #pragma unroll
    for (int o = 32; o; o >>= 1) v += __shfl_xor(v, o);
    __syncthreads();
    if ((threadIdx.x & 63) == 0) sc[threadIdx.x >> 6] = v;
    __syncthreads();
    return sc[0] + sc[1] + sc[2] + sc[3];
}
__device__ __forceinline__ float blk_max(float v, float* sc) {
    #pragma unroll
    for (int o = 32; o; o >>= 1) v = fmaxf(v, __shfl_xor(v, o));
    __syncthreads();
    if ((threadIdx.x & 63) == 0) sc[threadIdx.x >> 6] = v;
    __syncthreads();
    return fmaxf(fmaxf(sc[0], sc[1]), fmaxf(sc[2], sc[3]));
}

// threshold_gate: writes gate values g[c] in-place into eg[].
// Keep rule: element kept iff (#strictly greater) < TOPK  ==  eg >= kth_largest.
__device__ void threshold_gate_blk(const float* act, const float* msk, float tau,
                                   float* eg, float* sc) {
    __syncthreads();  // protect eg[] from previous readers
    for (int c = threadIdx.x; c < NCAND; c += 256) {
        float s    = (msk[c] != 0.f) ? act[c] : -1e9f;
        float raw  = s - tau;
        float gate = (raw > 0.f) ? raw : 1e-8f * expf(raw);
        eg[c] = expf(gate) - 1.f;
    }
    __syncthreads();
    const int t = threadIdx.x;
    float e0 = eg[t];
    float e1 = (t < NCAND - 256) ? eg[t + 256] : 0.f;
    int c0 = 0, c1 = 0;
    for (int j = 0; j < NCAND; j++) {
        float ej = eg[j];          // LDS broadcast across all threads
        c0 += (ej > e0);
        c1 += (ej > e1);
    }
    float w0 = (c0 < TOPK) ? e0 : 0.f;
    float w1 = (t < NCAND - 256 && c1 < TOPK) ? e1 : 0.f;
    float gs = blk_sum(w0 + w1, sc) + 1e-8f;        // barrier: all eg reads done
    float mx = blk_max(fmaxf(w0, w1), sc);          // eg >= 0 always (gate >= 0)
    float scale = tanhf(mx) / gs;
    eg[t] = w0 * scale;
    if (t < NCAND - 256) eg[t + 256] = w1 * scale;
    __syncthreads();
}

// ---------- kernel 1: per-token candidates, activations, gates, QKV, pos-loss ----------
__global__ __launch_bounds__(256) void qkv_kernel(
    const float* __restrict__ x, const float* __restrict__ qk_pos,
    const float* __restrict__ v_pos, const float* __restrict__ tauQ,
    const float* __restrict__ tauK, const float* __restrict__ tauV,
    const float* __restrict__ qk_neurons, const float* __restrict__ v_neurons,
    const float* __restrict__ npos_qk, const float* __restrict__ npos_v,
    const int* __restrict__ cm_qk, const int* __restrict__ cm_v,
    const float* __restrict__ pos_min, const float* __restrict__ pos_range,
    float* __restrict__ Q, float* __restrict__ K, float* __restrict__ V,
    float* __restrict__ posacc)
{
    __shared__ int   idx_qk[NCAND], idx_v[NCAND];
    __shared__ float mk[NCAND], mv[NCAND];
    __shared__ float act_qk[NCAND], act_v[NCAND];
    __shared__ float eg[NCAND];
    __shared__ float wq[NCAND], wk[NCAND], wv[NCAND];
    __shared__ float sc[4];

    const int token = blockIdx.x;
    const int b = token >> 10, s = token & 1023;
    (void)b;
    const int t = threadIdx.x;

    // --- candidate setup ---
    const float qp0 = qk_pos[token * 2], qp1 = qk_pos[token * 2 + 1];
    const float vp0 = v_pos[token * 2],  vp1 = v_pos[token * 2 + 1];
    const float pm0 = pos_min[0], pm1 = pos_min[1];
    const float pr0 = pos_range[0], pr1 = pos_range[1];
    const int cqx = min(max((int)((qp0 - pm0) / pr0 * 16.f), 0), 15);
    const int cqy = min(max((int)((qp1 - pm1) / pr1 * 16.f), 0), 15);
    const int cvx = min(max((int)((vp0 - pm0) / pr0 * 16.f), 0), 15);
    const int cvy = min(max((int)((vp1 - pm1) / pr1 * 16.f), 0), 15);
    for (int c = t; c < NCAND; c += 256) {
        const int o = c >> 5, m = c & 31;
        const int dx = o / 3 - 1, dy = o % 3 - 1;
        int nx, ny, cand;
        nx = min(max(cqx + dx, 0), 15); ny = min(max(cqy + dy, 0), 15);
        cand = cm_qk[(nx * 16 + ny) * 32 + m];
        idx_qk[c] = cand >= 0 ? cand : 0;  mk[c] = cand >= 0 ? 1.f : 0.f;
        nx = min(max(cvx + dx, 0), 15); ny = min(max(cvy + dy, 0), 15);
        cand = cm_v[(nx * 16 + ny) * 32 + m];
        idx_v[c] = cand >= 0 ? cand : 0;   mv[c] = cand >= 0 ? 1.f : 0.f;
    }
    __syncthreads();

    // --- activations: wave-per-candidate, lane holds 8 contiguous x values ---
    const int wid = t >> 6, lane = t & 63;
    const float4* x4 = (const float4*)(x + (size_t)token * D_);
    const float4 xa = x4[lane * 2], xb = x4[lane * 2 + 1];
    for (int c = wid * 72; c < wid * 72 + 72; ++c) {
        const float4* r4 = (const float4*)(qk_neurons + (size_t)idx_qk[c] * D_);
        float4 ra = r4[lane * 2], rb = r4[lane * 2 + 1];
        float a = xa.x * ra.x + xa.y * ra.y + xa.z * ra.z + xa.w * ra.w +
                  xb.x * rb.x + xb.y * rb.y + xb.z * rb.z + xb.w * rb.w;
        #pragma unroll
        for (int o = 32; o; o >>= 1) a += __shfl_xor(a, o);
        if (lane == 0) act_qk[c] = a;
    }
    for (int c = wid * 72; c < wid * 72 + 72; ++c) {
        const float4* r4 = (const float4*)(v_neurons + (size_t)idx_v[c] * D_);
        float4 ra = r4[lane * 2], rb = r4[lane * 2 + 1];
        float a = xa.x * ra.x + xa.y * ra.y + xa.z * ra.z + xa.w * ra.w +
                  xb.x * rb.x + xb.y * rb.y + xb.z * rb.z + xb.w * rb.w;
        #pragma unroll
        for (int o = 32; o; o >>= 1) a += __shfl_xor(a, o);
        if (lane == 0) act_v[c] = a;
    }
    __syncthreads();

    const float tq = tauQ[token], tk = tauK[token], tvv = tauV[token];

    // --- gate Q (+ pos-loss qk numerator & count) ---
    threshold_gate_blk(act_qk, mk, tq, eg, sc);
    float plq = 0.f, cntq = 0.f;
    for (int c = t; c < NCAND; c += 256) {
        float g = eg[c];
        wq[c] = act_qk[c] * g * mk[c];
        int id = idx_qk[c];
        float d0 = qp0 - npos_qk[id * 2], d1 = qp1 - npos_qk[id * 2 + 1];
        plq  += g * (d0 * d0 + d1 * d1) * mk[c];
        cntq += mk[c];
    }
    plq  = blk_sum(plq, sc);
    cntq = blk_sum(cntq, sc);

    // --- gate K ---
    threshold_gate_blk(act_qk, mk, tk, eg, sc);
    for (int c = t; c < NCAND; c += 256) wk[c] = act_qk[c] * eg[c] * mk[c];

    // --- gate V (+ pos-loss v numerator & count) ---
    threshold_gate_blk(act_v, mv, tvv, eg, sc);
    float plv = 0.f, cntv = 0.f;
    for (int c = t; c < NCAND; c += 256) {
        float g = eg[c];
        wv[c] = act_v[c] * g * mv[c];
        int id = idx_v[c];
        float d0 = vp0 - npos_v[id * 2], d1 = vp1 - npos_v[id * 2 + 1];
        plv  += g * (d0 * d0 + d1 * d1) * mv[c];
        cntv += mv[c];
    }
    plv  = blk_sum(plv, sc);
    cntv = blk_sum(cntv, sc);

    if (t == 0) {
        const int chunk = s >> 7;  // s / 128, summed over both batches per ref
        atomicAdd(&posacc[chunk],      plq);
        atomicAdd(&posacc[8 + chunk],  cntq);
        atomicAdd(&posacc[16 + chunk], plv);
        atomicAdd(&posacc[24 + chunk], cntv);
    }
    __syncthreads();

    // --- accumulate Q,K,V (thread t handles dims t and t+256) ---
    float q0 = 0, q1 = 0, k0 = 0, k1 = 0;
    for (int c = 0; c < NCAND; c++) {
        float a = wq[c], bb = wk[c];
        if (a == 0.f && bb == 0.f) continue;   // uniform branch (LDS broadcast)
        const float* row = qk_neurons + (size_t)idx_qk[c] * D_;
        float r0 = row[t], r1 = row[t + 256];
        q0 += a * r0;  q1 += a * r1;
        k0 += bb * r0; k1 += bb * r1;
    }
    const size_t base = (size_t)token * D_;
    Q[base + t] = q0;  Q[base + t + 256] = q1;
    K[base + t] = k0;  K[base + t + 256] = k1;

    float v0 = 0, v1 = 0;
    for (int c = 0; c < NCAND; c++) {
        float a = wv[c];
        if (a == 0.f) continue;
        const float* row = v_neurons + (size_t)idx_v[c] * D_;
        v0 += a * row[t];  v1 += a * row[t + 256];
    }
    V[base + t] = v0;  V[base + t + 256] = v1;
}

// ---------- kernel 2: causal attention, one wave per (b,h,row), online softmax ----------
__global__ __launch_bounds__(256) void attn_kernel(
    const float* __restrict__ Q, const float* __restrict__ K,
    const float* __restrict__ V, float* __restrict__ O)
{
    const int wid = threadIdx.x >> 6, lane = threadIdx.x & 63;
    const int r = blockIdx.x * 4 + wid;      // [0, B*H*S)
    const int b = r >> 13;                    // / (H*S)
    const int h = (r >> 10) & 7;
    const int i = r & 1023;

    const size_t tok = (size_t)(b * S_ + i);
    const float ql = Q[tok * D_ + h * DH_ + lane];
    const float* Kb = K + (size_t)b * S_ * D_ + h * DH_;
    const float* Vb = V + (size_t)b * S_ * D_ + h * DH_;

    float m = -INFINITY, l = 0.f, o = 0.f;
    for (int j = 0; j <= i; j++) {
        float sc = ql * Kb[(size_t)j * D_ + lane];
        #pragma unroll
        for (int off = 32; off; off >>= 1) sc += __shfl_xor(sc, off);
        sc *= 0.125f;                         // 1/sqrt(64)
        float nm = fmaxf(m, sc);
        float scale = expf(m - nm);           // first iter: exp(-inf)=0
        float p = expf(sc - nm);
        l = l * scale + p;
        o = o * scale + p * Vb[(size_t)j * D_ + lane];
        m = nm;
    }
    O[tok * D_ + h * DH_ + lane] = o / l;
}

// ---------- kernel 3: out = attn_out @ expand_O ----------
__global__ __launch_bounds__(256) void proj_kernel(
    const float* __restrict__ A, const float* __restrict__ W,
    float* __restrict__ out)
{
    __shared__ float row[D_];
    const int token = blockIdx.x;
    const int t = threadIdx.x;
    const float* a = A + (size_t)token * D_;
    for (int d = t; d < D_; d += 256) row[d] = a[d];
    __syncthreads();
    float a0 = 0.f, a1 = 0.f;
    for (int d = 0; d < D_; d++) {
        float rv = row[d];
        a0 += rv * W[(size_t)d * D_ + t];
        a1 += rv * W[(size_t)d * D_ + t + 256];
    }
    out[(size_t)token * D_ + t] = a0;
    out[(size_t)token * D_ + t + 256] = a1;
}

// ---------- pos-loss helpers ----------
__global__ void zero_acc_kernel(float* acc) {
    if (threadIdx.x < 32) acc[threadIdx.x] = 0.f;
}
__global__ void ploss_kernel(const float* __restrict__ acc, float* __restrict__ out) {
    float ssum = 0.f;
    for (int c = 0; c < 8; c++) {
        ssum += acc[c]      / (acc[8 + c]  + 1e-8f);
        ssum += acc[16 + c] / (acc[24 + c] + 1e-8f);
    }
    out[0] = ssum * 0.125f;   // mean over 8 chunks
}

extern "C" void kernel_launch(void* const* d_in, const int* in_sizes, int n_in,
                              void* d_out, int out_size, void* d_ws, size_t ws_size,
                              hipStream_t stream) {
    const float* x          = (const float*)d_in[0];
    const float* qk_pos     = (const float*)d_in[1];
    const float* v_pos      = (const float*)d_in[2];
    const float* tauQ       = (const float*)d_in[3];
    const float* tauK       = (const float*)d_in[4];
    const float* tauV       = (const float*)d_in[5];
    const float* qk_neurons = (const float*)d_in[6];
    const float* v_neurons  = (const float*)d_in[7];
    const float* npos_qk    = (const float*)d_in[8];
    const float* npos_v     = (const float*)d_in[9];
    const int*   cm_qk      = (const int*)d_in[10];
    const int*   cm_v       = (const int*)d_in[11];
    const float* pos_min    = (const float*)d_in[12];
    const float* pos_range  = (const float*)d_in[13];
    const float* expand_O   = (const float*)d_in[14];

    float* ws  = (float*)d_ws;
    float* Q   = ws;
    float* K   = ws + (size_t)NTOK * D_;
    float* V   = ws + (size_t)2 * NTOK * D_;
    float* AO  = ws + (size_t)3 * NTOK * D_;
    float* acc = ws + (size_t)4 * NTOK * D_;   // 32 floats

    float* out = (float*)d_out;

    zero_acc_kernel<<<1, 64, 0, stream>>>(acc);
    qkv_kernel<<<NTOK, 256, 0, stream>>>(x, qk_pos, v_pos, tauQ, tauK, tauV,
                                         qk_neurons, v_neurons, npos_qk, npos_v,
                                         cm_qk, cm_v, pos_min, pos_range,
                                         Q, K, V, acc);
    attn_kernel<<<(B_ * H_ * S_) / 4, 256, 0, stream>>>(Q, K, V, AO);
    proj_kernel<<<NTOK, 256, 0, stream>>>(AO, expand_O, out);
    ploss_kernel<<<1, 1, 0, stream>>>(acc, out + (size_t)NTOK * D_);
}

// Round 2
// 537.874 us; speedup vs baseline: 2.3804x; 2.3804x over previous
//
#include <hip/hip_runtime.h>
#include <math.h>

#define B_ 2
#define S_ 1024
#define D_ 512
#define N_ 4096
#define H_ 8
#define DH_ 64
#define NCAND 288   // 9 neighbor cells * 32 entries
#define TOPK 32
#define NTOK (B_*S_)   // 2048

// attention tiling
#define TJ 16        // j-tile per LDS stage
#define JSPAN 128    // j-range per split
#define NSPLIT 8
#define NROWS 16384  // B*H*S

// ---------- block-wide reductions (256 threads = 4 waves) ----------
__device__ __forceinline__ float blk_sum(float v, float* sc) {
    #pragma unroll
    for (int o = 32; o; o >>= 1) v += __shfl_xor(v, o);
    __syncthreads();
    if ((threadIdx.x & 63) == 0) sc[threadIdx.x >> 6] = v;
    __syncthreads();
    return sc[0] + sc[1] + sc[2] + sc[3];
}
__device__ __forceinline__ float blk_max(float v, float* sc) {
    #pragma unroll
    for (int o = 32; o; o >>= 1) v = fmaxf(v, __shfl_xor(v, o));
    __syncthreads();
    if ((threadIdx.x & 63) == 0) sc[threadIdx.x >> 6] = v;
    __syncthreads();
    return fmaxf(fmaxf(sc[0], sc[1]), fmaxf(sc[2], sc[3]));
}

// threshold_gate: writes gate values g[c] in-place into eg[].
// Keep rule: element kept iff (#strictly greater) < TOPK  ==  eg >= kth_largest.
__device__ void threshold_gate_blk(const float* act, const float* msk, float tau,
                                   float* eg, float* sc) {
    __syncthreads();  // protect eg[] from previous readers
    for (int c = threadIdx.x; c < NCAND; c += 256) {
        float s    = (msk[c] != 0.f) ? act[c] : -1e9f;
        float raw  = s - tau;
        float gate = (raw > 0.f) ? raw : 1e-8f * expf(raw);
        eg[c] = expf(gate) - 1.f;
    }
    __syncthreads();
    const int t = threadIdx.x;
    float e0 = eg[t];
    float e1 = (t < NCAND - 256) ? eg[t + 256] : 0.f;
    int c0 = 0, c1 = 0;
    for (int j = 0; j < NCAND; j++) {
        float ej = eg[j];          // LDS broadcast across all threads
        c0 += (ej > e0);
        c1 += (ej > e1);
    }
    float w0 = (c0 < TOPK) ? e0 : 0.f;
    float w1 = (t < NCAND - 256 && c1 < TOPK) ? e1 : 0.f;
    float gs = blk_sum(w0 + w1, sc) + 1e-8f;        // barrier: all eg reads done
    float mx = blk_max(fmaxf(w0, w1), sc);          // eg >= 0 always (gate >= 0)
    float scale = tanhf(mx) / gs;
    eg[t] = w0 * scale;
    if (t < NCAND - 256) eg[t + 256] = w1 * scale;
    __syncthreads();
}

// ---------- kernel 1: per-token candidates, activations, gates, QKV, pos-loss ----------
__global__ __launch_bounds__(256) void qkv_kernel(
    const float* __restrict__ x, const float* __restrict__ qk_pos,
    const float* __restrict__ v_pos, const float* __restrict__ tauQ,
    const float* __restrict__ tauK, const float* __restrict__ tauV,
    const float* __restrict__ qk_neurons, const float* __restrict__ v_neurons,
    const float* __restrict__ npos_qk, const float* __restrict__ npos_v,
    const int* __restrict__ cm_qk, const int* __restrict__ cm_v,
    const float* __restrict__ pos_min, const float* __restrict__ pos_range,
    float* __restrict__ Q, float* __restrict__ K, float* __restrict__ V,
    float* __restrict__ posacc)
{
    __shared__ int   idx_qk[NCAND], idx_v[NCAND];
    __shared__ float mk[NCAND], mv[NCAND];
    __shared__ float act_qk[NCAND], act_v[NCAND];
    __shared__ float eg[NCAND];
    __shared__ float wq[NCAND], wk[NCAND], wv[NCAND];
    __shared__ float sc[4];

    const int token = blockIdx.x;
    const int b = token >> 10, s = token & 1023;
    (void)b;
    const int t = threadIdx.x;

    // --- candidate setup ---
    const float qp0 = qk_pos[token * 2], qp1 = qk_pos[token * 2 + 1];
    const float vp0 = v_pos[token * 2],  vp1 = v_pos[token * 2 + 1];
    const float pm0 = pos_min[0], pm1 = pos_min[1];
    const float pr0 = pos_range[0], pr1 = pos_range[1];
    const int cqx = min(max((int)((qp0 - pm0) / pr0 * 16.f), 0), 15);
    const int cqy = min(max((int)((qp1 - pm1) / pr1 * 16.f), 0), 15);
    const int cvx = min(max((int)((vp0 - pm0) / pr0 * 16.f), 0), 15);
    const int cvy = min(max((int)((vp1 - pm1) / pr1 * 16.f), 0), 15);
    for (int c = t; c < NCAND; c += 256) {
        const int o = c >> 5, m = c & 31;
        const int dx = o / 3 - 1, dy = o % 3 - 1;
        int nx, ny, cand;
        nx = min(max(cqx + dx, 0), 15); ny = min(max(cqy + dy, 0), 15);
        cand = cm_qk[(nx * 16 + ny) * 32 + m];
        idx_qk[c] = cand >= 0 ? cand : 0;  mk[c] = cand >= 0 ? 1.f : 0.f;
        nx = min(max(cvx + dx, 0), 15); ny = min(max(cvy + dy, 0), 15);
        cand = cm_v[(nx * 16 + ny) * 32 + m];
        idx_v[c] = cand >= 0 ? cand : 0;   mv[c] = cand >= 0 ? 1.f : 0.f;
    }
    __syncthreads();

    // --- activations: wave-per-candidate, lane holds 8 contiguous x values ---
    const int wid = t >> 6, lane = t & 63;
    const float4* x4 = (const float4*)(x + (size_t)token * D_);
    const float4 xa = x4[lane * 2], xb = x4[lane * 2 + 1];
    for (int c = wid * 72; c < wid * 72 + 72; ++c) {
        const float4* r4 = (const float4*)(qk_neurons + (size_t)idx_qk[c] * D_);
        float4 ra = r4[lane * 2], rb = r4[lane * 2 + 1];
        float a = xa.x * ra.x + xa.y * ra.y + xa.z * ra.z + xa.w * ra.w +
                  xb.x * rb.x + xb.y * rb.y + xb.z * rb.z + xb.w * rb.w;
        #pragma unroll
        for (int o = 32; o; o >>= 1) a += __shfl_xor(a, o);
        if (lane == 0) act_qk[c] = a;
    }
    for (int c = wid * 72; c < wid * 72 + 72; ++c) {
        const float4* r4 = (const float4*)(v_neurons + (size_t)idx_v[c] * D_);
        float4 ra = r4[lane * 2], rb = r4[lane * 2 + 1];
        float a = xa.x * ra.x + xa.y * ra.y + xa.z * ra.z + xa.w * ra.w +
                  xb.x * rb.x + xb.y * rb.y + xb.z * rb.z + xb.w * rb.w;
        #pragma unroll
        for (int o = 32; o; o >>= 1) a += __shfl_xor(a, o);
        if (lane == 0) act_v[c] = a;
    }
    __syncthreads();

    const float tq = tauQ[token], tk = tauK[token], tvv = tauV[token];

    // --- gate Q (+ pos-loss qk numerator & count) ---
    threshold_gate_blk(act_qk, mk, tq, eg, sc);
    float plq = 0.f, cntq = 0.f;
    for (int c = t; c < NCAND; c += 256) {
        float g = eg[c];
        wq[c] = act_qk[c] * g * mk[c];
        int id = idx_qk[c];
        float d0 = qp0 - npos_qk[id * 2], d1 = qp1 - npos_qk[id * 2 + 1];
        plq  += g * (d0 * d0 + d1 * d1) * mk[c];
        cntq += mk[c];
    }
    plq  = blk_sum(plq, sc);
    cntq = blk_sum(cntq, sc);

    // --- gate K ---
    threshold_gate_blk(act_qk, mk, tk, eg, sc);
    for (int c = t; c < NCAND; c += 256) wk[c] = act_qk[c] * eg[c] * mk[c];

    // --- gate V (+ pos-loss v numerator & count) ---
    threshold_gate_blk(act_v, mv, tvv, eg, sc);
    float plv = 0.f, cntv = 0.f;
    for (int c = t; c < NCAND; c += 256) {
        float g = eg[c];
        wv[c] = act_v[c] * g * mv[c];
        int id = idx_v[c];
        float d0 = vp0 - npos_v[id * 2], d1 = vp1 - npos_v[id * 2 + 1];
        plv  += g * (d0 * d0 + d1 * d1) * mv[c];
        cntv += mv[c];
    }
    plv  = blk_sum(plv, sc);
    cntv = blk_sum(cntv, sc);

    if (t == 0) {
        const int chunk = s >> 7;  // s / 128, summed over both batches per ref
        atomicAdd(&posacc[chunk],      plq);
        atomicAdd(&posacc[8 + chunk],  cntq);
        atomicAdd(&posacc[16 + chunk], plv);
        atomicAdd(&posacc[24 + chunk], cntv);
    }
    __syncthreads();

    // --- accumulate Q,K,V (thread t handles dims t and t+256) ---
    float q0 = 0, q1 = 0, k0 = 0, k1 = 0;
    for (int c = 0; c < NCAND; c++) {
        float a = wq[c], bb = wk[c];
        if (a == 0.f && bb == 0.f) continue;   // uniform branch (LDS broadcast)
        const float* row = qk_neurons + (size_t)idx_qk[c] * D_;
        float r0 = row[t], r1 = row[t + 256];
        q0 += a * r0;  q1 += a * r1;
        k0 += bb * r0; k1 += bb * r1;
    }
    const size_t base = (size_t)token * D_;
    Q[base + t] = q0;  Q[base + t + 256] = q1;
    K[base + t] = k0;  K[base + t + 256] = k1;

    float v0 = 0, v1 = 0;
    for (int c = 0; c < NCAND; c++) {
        float a = wv[c];
        if (a == 0.f) continue;
        const float* row = v_neurons + (size_t)idx_v[c] * D_;
        v0 += a * row[t];  v1 += a * row[t + 256];
    }
    V[base + t] = v0;  V[base + t + 256] = v1;
}

// ---------- kernel 2a: flash-style causal attention partials ----------
// Thread-per-query-row: q[64], o[64] in registers; K/V tile in LDS read as
// wave-uniform broadcasts (all lanes process the same j simultaneously).
// Grid: (bh=16) x (row-block=4 of 256 rows) x (j-split=8 of 128).
__global__ __launch_bounds__(256, 2) void attn_partial_kernel(
    const float* __restrict__ Q, const float* __restrict__ K,
    const float* __restrict__ V,
    float* __restrict__ pm, float* __restrict__ pl, float* __restrict__ po)
{
    const int gb = blockIdx.x;
    const int sp = gb & 7;
    const int rb = (gb >> 3) & 3;
    const int bh = gb >> 5;            // 0..15
    const int b  = bh >> 3, h = bh & 7;
    const int maxi = rb * 256 + 255;
    const int j0 = sp * JSPAN;
    if (j0 > maxi) return;             // block-uniform early exit

    const int t = threadIdx.x;
    const int i = rb * 256 + t;        // this thread's query row

    __shared__ float Kl[TJ][68];       // pad 68: breaks write conflicts; reads are broadcast
    __shared__ float Vl[TJ][68];

    float q[64];
    {
        const float4* q4 = (const float4*)(Q + ((size_t)(b * S_ + i)) * D_ + h * DH_);
        #pragma unroll
        for (int k = 0; k < 16; k++) {
            float4 v = q4[k];
            q[4*k] = v.x; q[4*k+1] = v.y; q[4*k+2] = v.z; q[4*k+3] = v.w;
        }
    }
    float o[64];
    #pragma unroll
    for (int d = 0; d < 64; d++) o[d] = 0.f;
    float m = -INFINITY, l = 0.f;

    const int ntiles = min(JSPAN / TJ, (maxi - j0) / TJ + 1);
    const int ldrow = t >> 4, ldc = t & 15;
    const float* Kbase = K + (size_t)b * S_ * D_ + h * DH_;
    const float* Vbase = V + (size_t)b * S_ * D_ + h * DH_;

    for (int tile = 0; tile < ntiles; tile++) {
        const int jb = j0 + tile * TJ;
        __syncthreads();
        {
            const size_t off = (size_t)(jb + ldrow) * D_ + ldc * 4;
            float4 kv = *(const float4*)(Kbase + off);
            Kl[ldrow][ldc*4+0] = kv.x; Kl[ldrow][ldc*4+1] = kv.y;
            Kl[ldrow][ldc*4+2] = kv.z; Kl[ldrow][ldc*4+3] = kv.w;
            float4 vv = *(const float4*)(Vbase + off);
            Vl[ldrow][ldc*4+0] = vv.x; Vl[ldrow][ldc*4+1] = vv.y;
            Vl[ldrow][ldc*4+2] = vv.z; Vl[ldrow][ldc*4+3] = vv.w;
        }
        __syncthreads();
        if (jb > i) continue;          // divergence only between barriers; trip count uniform

        // scores for this tile: 4 independent accumulator chains for ILP
        float s[TJ];
        #pragma unroll
        for (int jj = 0; jj < TJ; jj++) {
            float a0 = 0.f, a1 = 0.f, a2 = 0.f, a3 = 0.f;
            #pragma unroll
            for (int d = 0; d < 64; d += 4) {
                a0 += q[d]   * Kl[jj][d];
                a1 += q[d+1] * Kl[jj][d+1];
                a2 += q[d+2] * Kl[jj][d+2];
                a3 += q[d+3] * Kl[jj][d+3];
            }
            float scv = ((a0 + a1) + (a2 + a3)) * 0.125f;   // 1/sqrt(64)
            s[jj] = (jb + jj <= i) ? scv : -INFINITY;
        }
        float tm = s[0];
        #pragma unroll
        for (int jj = 1; jj < TJ; jj++) tm = fmaxf(tm, s[jj]);
        const float nm = fmaxf(m, tm);                      // finite: s[0] valid (jb<=i)
        const float alpha = __expf(m - nm);                 // first tile: exp(-inf)=0
        float psum = 0.f;
        #pragma unroll
        for (int jj = 0; jj < TJ; jj++) { s[jj] = __expf(s[jj] - nm); psum += s[jj]; }
        l = l * alpha + psum;
        #pragma unroll
        for (int d = 0; d < 64; d++) o[d] *= alpha;
        #pragma unroll
        for (int jj = 0; jj < TJ; jj++) {
            const float pj = s[jj];
            #pragma unroll
            for (int d = 0; d < 64; d++) o[d] += pj * Vl[jj][d];
        }
        m = nm;
    }

    const int r = bh * S_ + i;                 // global row id [0, NROWS)
    pm[(size_t)sp * NROWS + r] = m;
    pl[(size_t)sp * NROWS + r] = l;
    float* od = po + ((size_t)sp * NROWS + r) * 64;
    #pragma unroll
    for (int k = 0; k < 16; k++) {
        float4 v;
        v.x = o[4*k]; v.y = o[4*k+1]; v.z = o[4*k+2]; v.w = o[4*k+3];
        *(float4*)(od + 4*k) = v;
    }
}

// ---------- kernel 2b: merge j-split partials ----------
__global__ __launch_bounds__(256) void attn_combine_kernel(
    const float* __restrict__ pm, const float* __restrict__ pl,
    const float* __restrict__ po, float* __restrict__ AO)
{
    const int g = blockIdx.x * 256 + threadIdx.x;   // NROWS*64 threads
    const int r = g >> 6, d = g & 63;
    const int i = r & 1023, bh = r >> 10;
    const int b = bh >> 3, h = bh & 7;
    const int ns = (i >> 7) + 1;                    // splits with >=1 valid j
    float mstar = -INFINITY;
    for (int s = 0; s < ns; s++) mstar = fmaxf(mstar, pm[s * NROWS + r]);
    float lstar = 0.f, ostar = 0.f;
    for (int s = 0; s < ns; s++) {
        const float w = __expf(pm[s * NROWS + r] - mstar);
        lstar += pl[s * NROWS + r] * w;
        ostar += po[((size_t)s * NROWS + r) * 64 + d] * w;
    }
    AO[((size_t)(b * S_ + i)) * D_ + h * DH_ + d] = ostar / lstar;
}

// ---------- kernel 3: out = attn_out @ expand_O ----------
__global__ __launch_bounds__(256) void proj_kernel(
    const float* __restrict__ A, const float* __restrict__ W,
    float* __restrict__ out)
{
    __shared__ float row[D_];
    const int token = blockIdx.x;
    const int t = threadIdx.x;
    const float* a = A + (size_t)token * D_;
    for (int d = t; d < D_; d += 256) row[d] = a[d];
    __syncthreads();
    float a0 = 0.f, a1 = 0.f;
    for (int d = 0; d < D_; d++) {
        float rv = row[d];
        a0 += rv * W[(size_t)d * D_ + t];
        a1 += rv * W[(size_t)d * D_ + t + 256];
    }
    out[(size_t)token * D_ + t] = a0;
    out[(size_t)token * D_ + t + 256] = a1;
}

// ---------- pos-loss helpers ----------
__global__ void zero_acc_kernel(float* acc) {
    if (threadIdx.x < 32) acc[threadIdx.x] = 0.f;
}
__global__ void ploss_kernel(const float* __restrict__ acc, float* __restrict__ out) {
    float ssum = 0.f;
    for (int c = 0; c < 8; c++) {
        ssum += acc[c]      / (acc[8 + c]  + 1e-8f);
        ssum += acc[16 + c] / (acc[24 + c] + 1e-8f);
    }
    out[0] = ssum * 0.125f;   // mean over 8 chunks
}

extern "C" void kernel_launch(void* const* d_in, const int* in_sizes, int n_in,
                              void* d_out, int out_size, void* d_ws, size_t ws_size,
                              hipStream_t stream) {
    const float* x          = (const float*)d_in[0];
    const float* qk_pos     = (const float*)d_in[1];
    const float* v_pos      = (const float*)d_in[2];
    const float* tauQ       = (const float*)d_in[3];
    const float* tauK       = (const float*)d_in[4];
    const float* tauV       = (const float*)d_in[5];
    const float* qk_neurons = (const float*)d_in[6];
    const float* v_neurons  = (const float*)d_in[7];
    const float* npos_qk    = (const float*)d_in[8];
    const float* npos_v     = (const float*)d_in[9];
    const int*   cm_qk      = (const int*)d_in[10];
    const int*   cm_v       = (const int*)d_in[11];
    const float* pos_min    = (const float*)d_in[12];
    const float* pos_range  = (const float*)d_in[13];
    const float* expand_O   = (const float*)d_in[14];

    float* ws  = (float*)d_ws;
    const size_t TD = (size_t)NTOK * D_;       // 1,048,576 floats
    float* Q   = ws;
    float* K   = ws + TD;
    float* V   = ws + 2 * TD;
    float* AO  = ws + 3 * TD;
    float* acc = ws + 4 * TD;                  // 32 floats (use 64 slot)
    float* pm  = acc + 64;                     // NSPLIT*NROWS
    float* pl  = pm + (size_t)NSPLIT * NROWS;
    float* po  = pl + (size_t)NSPLIT * NROWS;  // NSPLIT*NROWS*64

    float* out = (float*)d_out;

    zero_acc_kernel<<<1, 64, 0, stream>>>(acc);
    qkv_kernel<<<NTOK, 256, 0, stream>>>(x, qk_pos, v_pos, tauQ, tauK, tauV,
                                         qk_neurons, v_neurons, npos_qk, npos_v,
                                         cm_qk, cm_v, pos_min, pos_range,
                                         Q, K, V, acc);
    attn_partial_kernel<<<16 * 4 * NSPLIT, 256, 0, stream>>>(Q, K, V, pm, pl, po);
    attn_combine_kernel<<<(NROWS * 64) / 256, 256, 0, stream>>>(pm, pl, po, AO);
    proj_kernel<<<NTOK, 256, 0, stream>>>(AO, expand_O, out);
    ploss_kernel<<<1, 1, 0, stream>>>(acc, out + TD);
}